// Round 2
// baseline (564.874 us; speedup 1.0000x reference)
//
#include <hip/hip_runtime.h>
#include <stdint.h>

// ---------------------------------------------------------------------------
// aggregated_embedding: heap binary-tree aggregation, 11 levels.
// Per level: out = root + (elu(elu(x@WinT+b_in)@W1T+b1)@W2T+b2), x=[root,left,right]
// bf16 MFMA 16x16x32, fp32 accumulate. Round 4:
//  - MT=4 ELIMINATED. Under __launch_bounds__(256,4) the unified VGPR budget
//    is 128/wave; MT=4 needs 64 AGPR (acc) + ~90 arch (g[8]=32 held across
//    GEMM phases, bb=32, a[4]=16, addr) -> heavy scratch spill. rocprof
//    evidence: VGPR_Count=64 (forced 64+64 split), WRITE_SIZE 186MB vs
//    33.5MB ideal output (spill stores), WRITE > FETCH. Round-3 store
//    coalescing was invisible because traffic was spill, not output.
//  - MT=2 for all L>=256: acc=32 AGPR, g[4]=16, bb=32, a[2]=8 -> ~107/128
//    unified, no spill, still 4 blocks/CU, grid doubles (2048 @ L=1024).
//  - everything else identical to round 3 (single-variable experiment).
// ws layout:
//   [0)            Ebf   32064*256 bf16
//   [16,416,768)   Winbf 256*768  bf16   (row-major [n][k] = MFMA B-frag order)
//   [16,809,984)   W1bf  256*256  bf16
//   [16,941,056)   W2bf  256*256  bf16
//   [17,072,128)   curA  64*1024*256 bf16
//   [50,626,560)   curB  64*512*256 bf16
// ---------------------------------------------------------------------------

typedef __attribute__((ext_vector_type(8))) short short8;   // 8 x bf16 frag
typedef __attribute__((ext_vector_type(4))) float f32x4;    // MFMA C/D

#define XS_STRIDE 264   // 256+8 pad: row stride 528B, b128-aligned, 2-way bank alias (free)
#define TOK_N 4095

__device__ __forceinline__ unsigned short f32_to_bf16(float f) {
    union { float f; unsigned u; } v; v.f = f;
    return (unsigned short)((v.u + 0x7fffu + ((v.u >> 16) & 1u)) >> 16);  // RNE
}
__device__ __forceinline__ float bf16_to_f32(unsigned short u) {
    union { unsigned u; float f; } v; v.u = ((unsigned)u) << 16; return v.f;
}

__global__ void convert_f32_bf16(const float* __restrict__ E,
                                 const float* __restrict__ Win,
                                 const float* __restrict__ W1,
                                 const float* __restrict__ W2,
                                 unsigned short* __restrict__ Ebf,
                                 unsigned short* __restrict__ Winbf,
                                 unsigned short* __restrict__ W1bf,
                                 unsigned short* __restrict__ W2bf) {
    const int nE = 32064 * 256, nWin = 256 * 768, nW = 256 * 256;
    const int total4 = (nE + nWin + 2 * nW) >> 2;
    for (int i = blockIdx.x * blockDim.x + threadIdx.x; i < total4;
         i += gridDim.x * blockDim.x) {
        int idx = i << 2;
        const float* src; unsigned short* dst; int off;
        if (idx < nE)                  { src = E;   dst = Ebf;   off = idx; }
        else if (idx < nE + nWin)      { src = Win; dst = Winbf; off = idx - nE; }
        else if (idx < nE + nWin + nW) { src = W1;  dst = W1bf;  off = idx - nE - nWin; }
        else                           { src = W2;  dst = W2bf;  off = idx - nE - nWin - nW; }
        float4 f = *(const float4*)(src + off);
        ushort4 o;
        o.x = f32_to_bf16(f.x); o.y = f32_to_bf16(f.y);
        o.z = f32_to_bf16(f.z); o.w = f32_to_bf16(f.w);
        *(ushort4*)(dst + off) = o;
    }
}

// ---------------------------------------------------------------------------
// tree_level<MT>: block = 256 thr (4 waves), R = MT*16 rows x 256 cols.
// Wave owns 64-col slice (n0), MT x 4 grid of 16x16 MFMA tiles.
// A-frag: lane holds A[m=lane&15][k=quad*8+j]; B-frag: W row-major 16B chunk.
// ---------------------------------------------------------------------------
template<int MT>
__global__ __launch_bounds__(256, 4)
void tree_level(const int* __restrict__ tokens,
                const unsigned short* __restrict__ Ebf,
                const unsigned short* __restrict__ Win,
                const unsigned short* __restrict__ W1,
                const unsigned short* __restrict__ W2,
                const float* __restrict__ b_in,
                const float* __restrict__ b1,
                const float* __restrict__ b2,
                const unsigned short* __restrict__ cur_in,
                unsigned short* __restrict__ cur_out,
                float* __restrict__ final_out,
                int L, int logL, int first, int last)
{
    constexpr int R = MT * 16;
    constexpr int GITER = R / 8;          // 16B-chunk gather iters per thread
    __shared__ unsigned short Xs[R * XS_STRIDE];

    const int tid  = threadIdx.x;
    const int lane = tid & 63;
    const int wid  = tid >> 6;
    const int l15  = lane & 15;
    const int q    = lane >> 4;
    const int n0   = wid * 64;
    const int blk  = blockIdx.x;
    const int c    = tid & 31;            // 16B chunk within 512B row
    const int sub  = tid >> 5;            // 8 rows gathered in parallel

    // gather source for (phase p, local row r)
    auto gsrc = [&](int p, int r) -> const unsigned short* {
        int g = blk * R + r;
        int b = g >> logL;
        int i = g - (b << logL);
        if (p == 0) {
            int tok = tokens[b * TOK_N + (L - 1) + i];
            return Ebf + (size_t)tok * 256;
        } else if (first) {
            int tok = tokens[b * TOK_N + 2047 + 2 * i + (p - 1)];
            return Ebf + (size_t)tok * 256;
        } else {
            return cur_in + ((size_t)b * (2 * L) + 2 * i + (p - 1)) * 256;
        }
    };

    short8 g[GITER];

    // ---- phase-0 gather (root) ------------------------------------------
#pragma unroll
    for (int it = 0; it < GITER; ++it)
        g[it] = *(const short8*)(gsrc(0, it * 8 + sub) + c * 8);
#pragma unroll
    for (int it = 0; it < GITER; ++it)
        *(short8*)(&Xs[(it * 8 + sub) * XS_STRIDE + c * 8]) = g[it];
    __syncthreads();

    f32x4 acc[MT][4];
    float bv[4];
#pragma unroll
    for (int nt = 0; nt < 4; ++nt) bv[nt] = b_in[n0 + nt * 16 + l15];
#pragma unroll
    for (int mt = 0; mt < MT; ++mt)
#pragma unroll
        for (int nt = 0; nt < 4; ++nt)
            acc[mt][nt] = (f32x4){bv[nt], bv[nt], bv[nt], bv[nt]};

    // ---- GEMM1: 3 phases of K=256 against Win (row stride 768) ----------
    const unsigned short* wbase = Win + q * 8 + (size_t)(n0 + l15) * 768;
    for (int p = 0; p < 3; ++p) {
        const int kbase = p * 256;
        short8 bb[2][4];                              // rolling 2-kstep preload
#pragma unroll
        for (int k = 0; k < 2; ++k)
#pragma unroll
            for (int nt = 0; nt < 4; ++nt)
                bb[k][nt] = *(const short8*)(wbase + (size_t)(nt * 16) * 768 + kbase + k * 32);
        if (p < 2) {                                  // prefetch next gather
#pragma unroll
            for (int it = 0; it < GITER; ++it)
                g[it] = *(const short8*)(gsrc(p + 1, it * 8 + sub) + c * 8);
        }
#pragma unroll
        for (int k = 0; k < 8; ++k) {
            short8 a[MT];
#pragma unroll
            for (int mt = 0; mt < MT; ++mt)
                a[mt] = *(const short8*)(&Xs[(mt * 16 + l15) * XS_STRIDE + k * 32 + q * 8]);
#pragma unroll
            for (int mt = 0; mt < MT; ++mt)
#pragma unroll
                for (int nt = 0; nt < 4; ++nt)
                    acc[mt][nt] = __builtin_amdgcn_mfma_f32_16x16x32_bf16(
                        a[mt], bb[k & 1][nt], acc[mt][nt], 0, 0, 0);
            if (k + 2 < 8) {
#pragma unroll
                for (int nt = 0; nt < 4; ++nt)
                    bb[k & 1][nt] = *(const short8*)(wbase + (size_t)(nt * 16) * 768 + kbase + (k + 2) * 32);
            }
        }
        __syncthreads();                               // all waves done reading Xs
        if (p < 2) {
#pragma unroll
            for (int it = 0; it < GITER; ++it)
                *(short8*)(&Xs[(it * 8 + sub) * XS_STRIDE + c * 8]) = g[it];
            __syncthreads();
        }
    }

    // ---- epilogue 1: Xs = bf16(elu(H1)) in place ------------------------
#pragma unroll
    for (int mt = 0; mt < MT; ++mt)
#pragma unroll
        for (int nt = 0; nt < 4; ++nt)
#pragma unroll
            for (int r = 0; r < 4; ++r) {
                float h = acc[mt][nt][r];
                h = h > 0.f ? h : (__expf(h) - 1.f);
                Xs[(mt * 16 + q * 4 + r) * XS_STRIDE + n0 + nt * 16 + l15] = f32_to_bf16(h);
            }
    __syncthreads();

    // ---- GEMM2: H2 = elu(H1) @ W1^T  (+ root re-gather prefetch) --------
#pragma unroll
    for (int nt = 0; nt < 4; ++nt) bv[nt] = b1[n0 + nt * 16 + l15];
#pragma unroll
    for (int mt = 0; mt < MT; ++mt)
#pragma unroll
        for (int nt = 0; nt < 4; ++nt)
            acc[mt][nt] = (f32x4){bv[nt], bv[nt], bv[nt], bv[nt]};
    {
        const unsigned short* w1base = W1 + q * 8 + (size_t)(n0 + l15) * 256;
        short8 bb[2][4];
#pragma unroll
        for (int k = 0; k < 2; ++k)
#pragma unroll
            for (int nt = 0; nt < 4; ++nt)
                bb[k][nt] = *(const short8*)(w1base + (size_t)(nt * 16) * 256 + k * 32);
        // residual root (bf16) re-gather: issued here, consumed after GEMM3
#pragma unroll
        for (int it = 0; it < GITER; ++it)
            g[it] = *(const short8*)(gsrc(0, it * 8 + sub) + c * 8);
#pragma unroll
        for (int k = 0; k < 8; ++k) {
            short8 a[MT];
#pragma unroll
            for (int mt = 0; mt < MT; ++mt)
                a[mt] = *(const short8*)(&Xs[(mt * 16 + l15) * XS_STRIDE + k * 32 + q * 8]);
#pragma unroll
            for (int mt = 0; mt < MT; ++mt)
#pragma unroll
                for (int nt = 0; nt < 4; ++nt)
                    acc[mt][nt] = __builtin_amdgcn_mfma_f32_16x16x32_bf16(
                        a[mt], bb[k & 1][nt], acc[mt][nt], 0, 0, 0);
            if (k + 2 < 8) {
#pragma unroll
                for (int nt = 0; nt < 4; ++nt)
                    bb[k & 1][nt] = *(const short8*)(w1base + (size_t)(nt * 16) * 256 + (k + 2) * 32);
            }
        }
    }
    __syncthreads();

    // ---- epilogue 2: Xs = bf16(elu(H2)) in place ------------------------
#pragma unroll
    for (int mt = 0; mt < MT; ++mt)
#pragma unroll
        for (int nt = 0; nt < 4; ++nt)
#pragma unroll
            for (int r = 0; r < 4; ++r) {
                float h = acc[mt][nt][r];
                h = h > 0.f ? h : (__expf(h) - 1.f);
                Xs[(mt * 16 + q * 4 + r) * XS_STRIDE + n0 + nt * 16 + l15] = f32_to_bf16(h);
            }
    __syncthreads();

    // ---- GEMM3: H3 = elu(H2) @ W2^T -------------------------------------
#pragma unroll
    for (int nt = 0; nt < 4; ++nt) bv[nt] = b2[n0 + nt * 16 + l15];
#pragma unroll
    for (int mt = 0; mt < MT; ++mt)
#pragma unroll
        for (int nt = 0; nt < 4; ++nt)
            acc[mt][nt] = (f32x4){bv[nt], bv[nt], bv[nt], bv[nt]};
    {
        const unsigned short* w2base = W2 + q * 8 + (size_t)(n0 + l15) * 256;
        short8 bb[2][4];
#pragma unroll
        for (int k = 0; k < 2; ++k)
#pragma unroll
            for (int nt = 0; nt < 4; ++nt)
                bb[k][nt] = *(const short8*)(w2base + (size_t)(nt * 16) * 256 + k * 32);
#pragma unroll
        for (int k = 0; k < 8; ++k) {
            short8 a[MT];
#pragma unroll
            for (int mt = 0; mt < MT; ++mt)
                a[mt] = *(const short8*)(&Xs[(mt * 16 + l15) * XS_STRIDE + k * 32 + q * 8]);
#pragma unroll
            for (int mt = 0; mt < MT; ++mt)
#pragma unroll
                for (int nt = 0; nt < 4; ++nt)
                    acc[mt][nt] = __builtin_amdgcn_mfma_f32_16x16x32_bf16(
                        a[mt], bb[k & 1][nt], acc[mt][nt], 0, 0, 0);
            if (k + 2 < 8) {
#pragma unroll
                for (int nt = 0; nt < 4; ++nt)
                    bb[k & 1][nt] = *(const short8*)(w2base + (size_t)(nt * 16) * 256 + (k + 2) * 32);
            }
        }
    }
    __syncthreads();
    // park the root rows (bf16) in Xs for transposed access by the epilogue
#pragma unroll
    for (int it = 0; it < GITER; ++it)
        *(short8*)(&Xs[(it * 8 + sub) * XS_STRIDE + c * 8]) = g[it];
    __syncthreads();

    // ---- epilogue 3: out = root + H3 (+b2 already in acc), no elu -------
    if (last) {
        // final level: 4 blocks total, fp32 output, scalar path is fine
#pragma unroll
        for (int mt = 0; mt < MT; ++mt)
#pragma unroll
            for (int r = 0; r < 4; ++r) {
                int row = mt * 16 + q * 4 + r;
                int gg  = blk * R + row;
#pragma unroll
                for (int nt = 0; nt < 4; ++nt) {
                    int col = n0 + nt * 16 + l15;
                    float o = acc[mt][nt][r] + bf16_to_f32(Xs[row * XS_STRIDE + col]);
                    final_out[(size_t)gg * 256 + col] = o;
                }
            }
    } else {
        // add root into acc, write bf16 result back into Xs IN PLACE
        // (each thread reads+writes the exact same address: no race),
        // then store fully-coalesced short8 rows.
#pragma unroll
        for (int mt = 0; mt < MT; ++mt)
#pragma unroll
            for (int r = 0; r < 4; ++r) {
                int row = mt * 16 + q * 4 + r;
#pragma unroll
                for (int nt = 0; nt < 4; ++nt) {
                    int col = n0 + nt * 16 + l15;
                    float o = acc[mt][nt][r] + bf16_to_f32(Xs[row * XS_STRIDE + col]);
                    Xs[row * XS_STRIDE + col] = f32_to_bf16(o);
                }
            }
        __syncthreads();
#pragma unroll
        for (int it = 0; it < GITER; ++it) {
            int row = it * 8 + sub;
            *(short8*)(cur_out + ((size_t)(blk * R + row)) * 256 + c * 8) =
                *(const short8*)(&Xs[row * XS_STRIDE + c * 8]);
        }
    }
}

extern "C" void kernel_launch(void* const* d_in, const int* in_sizes, int n_in,
                              void* d_out, int out_size, void* d_ws, size_t ws_size,
                              hipStream_t stream) {
    const int*   tokens = (const int*)  d_in[0];
    const float* E      = (const float*)d_in[1];
    const float* W_in   = (const float*)d_in[2];
    const float* b_in   = (const float*)d_in[3];
    const float* W1     = (const float*)d_in[4];
    const float* b1     = (const float*)d_in[5];
    const float* W2     = (const float*)d_in[6];
    const float* b2     = (const float*)d_in[7];
    float* out = (float*)d_out;
    char* ws = (char*)d_ws;

    unsigned short* Ebf   = (unsigned short*)(ws);
    unsigned short* Winbf = (unsigned short*)(ws + 16416768);
    unsigned short* W1bf  = (unsigned short*)(ws + 16809984);
    unsigned short* W2bf  = (unsigned short*)(ws + 16941056);
    unsigned short* curA  = (unsigned short*)(ws + 17072128);
    unsigned short* curB  = (unsigned short*)(ws + 50626560);

    convert_f32_bf16<<<1024, 256, 0, stream>>>(E, W_in, W1, W2,
                                               Ebf, Winbf, W1bf, W2bf);

    const unsigned short* cin = curA;
    unsigned short* cout = curA;
    int first = 1;
    for (int L = 1024; L >= 1; L >>= 1) {
        int logL = 31 - __builtin_clz((unsigned)L);
        int last = (L == 1);
        // MT=2 for all big levels: MT=4 spilled (64 AGPR + ~90 arch > 128 cap)
        int MTs = (L >= 256) ? 2 : 1;
        int blocks = (64 * L) / (16 * MTs);
        if (MTs == 2)
            tree_level<2><<<dim3(blocks), dim3(256), 0, stream>>>(
                tokens, Ebf, Winbf, W1bf, W2bf, b_in, b1, b2,
                cin, last ? nullptr : cout, last ? out : nullptr, L, logL, first, last);
        else
            tree_level<1><<<dim3(blocks), dim3(256), 0, stream>>>(
                tokens, Ebf, Winbf, W1bf, W2bf, b_in, b1, b2,
                cin, last ? nullptr : cout, last ? out : nullptr, L, logL, first, last);
        cin = cout;
        cout = (cout == curA) ? curB : curA;
        first = 0;
    }
}

// Round 3
// 505.740 us; speedup vs baseline: 1.1169x; 1.1169x over previous
//
#include <hip/hip_runtime.h>
#include <stdint.h>

// ---------------------------------------------------------------------------
// aggregated_embedding: heap binary-tree aggregation, 11 levels.
// Per level: out = root + (elu(elu(x@WinT+b_in)@W1T+b1)@W2T+b2), x=[root,left,right]
// bf16 MFMA 16x16x32, fp32 accumulate. Round 5:
//  - MT=4 RESTORED (R=64): round-4's MT=2 proved traffic was spill (WRITE
//    186->41MB) but got SLOWER (137->170us): kernel is LATENCY-bound; MT=2
//    halved bb-preload L2 cover (78cy vs 155cy vs ~200cy L2 latency) and
//    doubled per-level weight L2 streaming (640KB/block, fixed).
//  - Spill fixed the other way: __launch_bounds__(256,3) for MT=4 -> 170
//    unified VGPR budget >= ~164 live set -> no spill, 3 blocks/CU.
//    MT=2/1 keep (256,4) (live set ~107 < 128, no spill).
//  - Coalesced LDS-staged epilogue-3 store kept from round 3.
// ws layout:
//   [0)            Ebf   32064*256 bf16
//   [16,416,768)   Winbf 256*768  bf16   (row-major [n][k] = MFMA B-frag order)
//   [16,809,984)   W1bf  256*256  bf16
//   [16,941,056)   W2bf  256*256  bf16
//   [17,072,128)   curA  64*1024*256 bf16
//   [50,626,560)   curB  64*512*256 bf16
// ---------------------------------------------------------------------------

typedef __attribute__((ext_vector_type(8))) short short8;   // 8 x bf16 frag
typedef __attribute__((ext_vector_type(4))) float f32x4;    // MFMA C/D

#define XS_STRIDE 264   // 256+8 pad: row stride 528B, b128-aligned, 2-way bank alias (free)
#define TOK_N 4095

__device__ __forceinline__ unsigned short f32_to_bf16(float f) {
    union { float f; unsigned u; } v; v.f = f;
    return (unsigned short)((v.u + 0x7fffu + ((v.u >> 16) & 1u)) >> 16);  // RNE
}
__device__ __forceinline__ float bf16_to_f32(unsigned short u) {
    union { unsigned u; float f; } v; v.u = ((unsigned)u) << 16; return v.f;
}

__global__ void convert_f32_bf16(const float* __restrict__ E,
                                 const float* __restrict__ Win,
                                 const float* __restrict__ W1,
                                 const float* __restrict__ W2,
                                 unsigned short* __restrict__ Ebf,
                                 unsigned short* __restrict__ Winbf,
                                 unsigned short* __restrict__ W1bf,
                                 unsigned short* __restrict__ W2bf) {
    const int nE = 32064 * 256, nWin = 256 * 768, nW = 256 * 256;
    const int total4 = (nE + nWin + 2 * nW) >> 2;
    for (int i = blockIdx.x * blockDim.x + threadIdx.x; i < total4;
         i += gridDim.x * blockDim.x) {
        int idx = i << 2;
        const float* src; unsigned short* dst; int off;
        if (idx < nE)                  { src = E;   dst = Ebf;   off = idx; }
        else if (idx < nE + nWin)      { src = Win; dst = Winbf; off = idx - nE; }
        else if (idx < nE + nWin + nW) { src = W1;  dst = W1bf;  off = idx - nE - nWin; }
        else                           { src = W2;  dst = W2bf;  off = idx - nE - nWin - nW; }
        float4 f = *(const float4*)(src + off);
        ushort4 o;
        o.x = f32_to_bf16(f.x); o.y = f32_to_bf16(f.y);
        o.z = f32_to_bf16(f.z); o.w = f32_to_bf16(f.w);
        *(ushort4*)(dst + off) = o;
    }
}

// ---------------------------------------------------------------------------
// tree_level<MT>: block = 256 thr (4 waves), R = MT*16 rows x 256 cols.
// Wave owns 64-col slice (n0), MT x 4 grid of 16x16 MFMA tiles.
// A-frag: lane holds A[m=lane&15][k=quad*8+j]; B-frag: W row-major 16B chunk.
// MT=4 runs at 3 waves/EU (170 VGPR budget, no spill); MT<=2 at 4 waves/EU.
// ---------------------------------------------------------------------------
template<int MT>
__global__ __launch_bounds__(256, (MT == 4) ? 3 : 4)
void tree_level(const int* __restrict__ tokens,
                const unsigned short* __restrict__ Ebf,
                const unsigned short* __restrict__ Win,
                const unsigned short* __restrict__ W1,
                const unsigned short* __restrict__ W2,
                const float* __restrict__ b_in,
                const float* __restrict__ b1,
                const float* __restrict__ b2,
                const unsigned short* __restrict__ cur_in,
                unsigned short* __restrict__ cur_out,
                float* __restrict__ final_out,
                int L, int logL, int first, int last)
{
    constexpr int R = MT * 16;
    constexpr int GITER = R / 8;          // 16B-chunk gather iters per thread
    __shared__ unsigned short Xs[R * XS_STRIDE];

    const int tid  = threadIdx.x;
    const int lane = tid & 63;
    const int wid  = tid >> 6;
    const int l15  = lane & 15;
    const int q    = lane >> 4;
    const int n0   = wid * 64;
    const int blk  = blockIdx.x;
    const int c    = tid & 31;            // 16B chunk within 512B row
    const int sub  = tid >> 5;            // 8 rows gathered in parallel

    // gather source for (phase p, local row r)
    auto gsrc = [&](int p, int r) -> const unsigned short* {
        int g = blk * R + r;
        int b = g >> logL;
        int i = g - (b << logL);
        if (p == 0) {
            int tok = tokens[b * TOK_N + (L - 1) + i];
            return Ebf + (size_t)tok * 256;
        } else if (first) {
            int tok = tokens[b * TOK_N + 2047 + 2 * i + (p - 1)];
            return Ebf + (size_t)tok * 256;
        } else {
            return cur_in + ((size_t)b * (2 * L) + 2 * i + (p - 1)) * 256;
        }
    };

    short8 g[GITER];

    // ---- phase-0 gather (root) ------------------------------------------
#pragma unroll
    for (int it = 0; it < GITER; ++it)
        g[it] = *(const short8*)(gsrc(0, it * 8 + sub) + c * 8);
#pragma unroll
    for (int it = 0; it < GITER; ++it)
        *(short8*)(&Xs[(it * 8 + sub) * XS_STRIDE + c * 8]) = g[it];
    __syncthreads();

    f32x4 acc[MT][4];
    float bv[4];
#pragma unroll
    for (int nt = 0; nt < 4; ++nt) bv[nt] = b_in[n0 + nt * 16 + l15];
#pragma unroll
    for (int mt = 0; mt < MT; ++mt)
#pragma unroll
        for (int nt = 0; nt < 4; ++nt)
            acc[mt][nt] = (f32x4){bv[nt], bv[nt], bv[nt], bv[nt]};

    // ---- GEMM1: 3 phases of K=256 against Win (row stride 768) ----------
    const unsigned short* wbase = Win + q * 8 + (size_t)(n0 + l15) * 768;
    for (int p = 0; p < 3; ++p) {
        const int kbase = p * 256;
        short8 bb[2][4];                              // rolling 2-kstep preload
#pragma unroll
        for (int k = 0; k < 2; ++k)
#pragma unroll
            for (int nt = 0; nt < 4; ++nt)
                bb[k][nt] = *(const short8*)(wbase + (size_t)(nt * 16) * 768 + kbase + k * 32);
        if (p < 2) {                                  // prefetch next gather
#pragma unroll
            for (int it = 0; it < GITER; ++it)
                g[it] = *(const short8*)(gsrc(p + 1, it * 8 + sub) + c * 8);
        }
#pragma unroll
        for (int k = 0; k < 8; ++k) {
            short8 a[MT];
#pragma unroll
            for (int mt = 0; mt < MT; ++mt)
                a[mt] = *(const short8*)(&Xs[(mt * 16 + l15) * XS_STRIDE + k * 32 + q * 8]);
#pragma unroll
            for (int mt = 0; mt < MT; ++mt)
#pragma unroll
                for (int nt = 0; nt < 4; ++nt)
                    acc[mt][nt] = __builtin_amdgcn_mfma_f32_16x16x32_bf16(
                        a[mt], bb[k & 1][nt], acc[mt][nt], 0, 0, 0);
            if (k + 2 < 8) {
#pragma unroll
                for (int nt = 0; nt < 4; ++nt)
                    bb[k & 1][nt] = *(const short8*)(wbase + (size_t)(nt * 16) * 768 + kbase + (k + 2) * 32);
            }
        }
        __syncthreads();                               // all waves done reading Xs
        if (p < 2) {
#pragma unroll
            for (int it = 0; it < GITER; ++it)
                *(short8*)(&Xs[(it * 8 + sub) * XS_STRIDE + c * 8]) = g[it];
            __syncthreads();
        }
    }

    // ---- epilogue 1: Xs = bf16(elu(H1)) in place ------------------------
#pragma unroll
    for (int mt = 0; mt < MT; ++mt)
#pragma unroll
        for (int nt = 0; nt < 4; ++nt)
#pragma unroll
            for (int r = 0; r < 4; ++r) {
                float h = acc[mt][nt][r];
                h = h > 0.f ? h : (__expf(h) - 1.f);
                Xs[(mt * 16 + q * 4 + r) * XS_STRIDE + n0 + nt * 16 + l15] = f32_to_bf16(h);
            }
    __syncthreads();

    // ---- GEMM2: H2 = elu(H1) @ W1^T  (+ root re-gather prefetch) --------
#pragma unroll
    for (int nt = 0; nt < 4; ++nt) bv[nt] = b1[n0 + nt * 16 + l15];
#pragma unroll
    for (int mt = 0; mt < MT; ++mt)
#pragma unroll
        for (int nt = 0; nt < 4; ++nt)
            acc[mt][nt] = (f32x4){bv[nt], bv[nt], bv[nt], bv[nt]};
    {
        const unsigned short* w1base = W1 + q * 8 + (size_t)(n0 + l15) * 256;
        short8 bb[2][4];
#pragma unroll
        for (int k = 0; k < 2; ++k)
#pragma unroll
            for (int nt = 0; nt < 4; ++nt)
                bb[k][nt] = *(const short8*)(w1base + (size_t)(nt * 16) * 256 + k * 32);
        // residual root (bf16) re-gather: issued here, consumed after GEMM3
#pragma unroll
        for (int it = 0; it < GITER; ++it)
            g[it] = *(const short8*)(gsrc(0, it * 8 + sub) + c * 8);
#pragma unroll
        for (int k = 0; k < 8; ++k) {
            short8 a[MT];
#pragma unroll
            for (int mt = 0; mt < MT; ++mt)
                a[mt] = *(const short8*)(&Xs[(mt * 16 + l15) * XS_STRIDE + k * 32 + q * 8]);
#pragma unroll
            for (int mt = 0; mt < MT; ++mt)
#pragma unroll
                for (int nt = 0; nt < 4; ++nt)
                    acc[mt][nt] = __builtin_amdgcn_mfma_f32_16x16x32_bf16(
                        a[mt], bb[k & 1][nt], acc[mt][nt], 0, 0, 0);
            if (k + 2 < 8) {
#pragma unroll
                for (int nt = 0; nt < 4; ++nt)
                    bb[k & 1][nt] = *(const short8*)(w1base + (size_t)(nt * 16) * 256 + (k + 2) * 32);
            }
        }
    }
    __syncthreads();

    // ---- epilogue 2: Xs = bf16(elu(H2)) in place ------------------------
#pragma unroll
    for (int mt = 0; mt < MT; ++mt)
#pragma unroll
        for (int nt = 0; nt < 4; ++nt)
#pragma unroll
            for (int r = 0; r < 4; ++r) {
                float h = acc[mt][nt][r];
                h = h > 0.f ? h : (__expf(h) - 1.f);
                Xs[(mt * 16 + q * 4 + r) * XS_STRIDE + n0 + nt * 16 + l15] = f32_to_bf16(h);
            }
    __syncthreads();

    // ---- GEMM3: H3 = elu(H2) @ W2^T -------------------------------------
#pragma unroll
    for (int nt = 0; nt < 4; ++nt) bv[nt] = b2[n0 + nt * 16 + l15];
#pragma unroll
    for (int mt = 0; mt < MT; ++mt)
#pragma unroll
        for (int nt = 0; nt < 4; ++nt)
            acc[mt][nt] = (f32x4){bv[nt], bv[nt], bv[nt], bv[nt]};
    {
        const unsigned short* w2base = W2 + q * 8 + (size_t)(n0 + l15) * 256;
        short8 bb[2][4];
#pragma unroll
        for (int k = 0; k < 2; ++k)
#pragma unroll
            for (int nt = 0; nt < 4; ++nt)
                bb[k][nt] = *(const short8*)(w2base + (size_t)(nt * 16) * 256 + k * 32);
#pragma unroll
        for (int k = 0; k < 8; ++k) {
            short8 a[MT];
#pragma unroll
            for (int mt = 0; mt < MT; ++mt)
                a[mt] = *(const short8*)(&Xs[(mt * 16 + l15) * XS_STRIDE + k * 32 + q * 8]);
#pragma unroll
            for (int mt = 0; mt < MT; ++mt)
#pragma unroll
                for (int nt = 0; nt < 4; ++nt)
                    acc[mt][nt] = __builtin_amdgcn_mfma_f32_16x16x32_bf16(
                        a[mt], bb[k & 1][nt], acc[mt][nt], 0, 0, 0);
            if (k + 2 < 8) {
#pragma unroll
                for (int nt = 0; nt < 4; ++nt)
                    bb[k & 1][nt] = *(const short8*)(w2base + (size_t)(nt * 16) * 256 + (k + 2) * 32);
            }
        }
    }
    __syncthreads();
    // park the root rows (bf16) in Xs for transposed access by the epilogue
#pragma unroll
    for (int it = 0; it < GITER; ++it)
        *(short8*)(&Xs[(it * 8 + sub) * XS_STRIDE + c * 8]) = g[it];
    __syncthreads();

    // ---- epilogue 3: out = root + H3 (+b2 already in acc), no elu -------
    if (last) {
        // final level: 4 blocks total, fp32 output, scalar path is fine
#pragma unroll
        for (int mt = 0; mt < MT; ++mt)
#pragma unroll
            for (int r = 0; r < 4; ++r) {
                int row = mt * 16 + q * 4 + r;
                int gg  = blk * R + row;
#pragma unroll
                for (int nt = 0; nt < 4; ++nt) {
                    int col = n0 + nt * 16 + l15;
                    float o = acc[mt][nt][r] + bf16_to_f32(Xs[row * XS_STRIDE + col]);
                    final_out[(size_t)gg * 256 + col] = o;
                }
            }
    } else {
        // add root into acc, write bf16 result back into Xs IN PLACE
        // (each thread reads+writes the exact same address: no race),
        // then store fully-coalesced short8 rows.
#pragma unroll
        for (int mt = 0; mt < MT; ++mt)
#pragma unroll
            for (int r = 0; r < 4; ++r) {
                int row = mt * 16 + q * 4 + r;
#pragma unroll
                for (int nt = 0; nt < 4; ++nt) {
                    int col = n0 + nt * 16 + l15;
                    float o = acc[mt][nt][r] + bf16_to_f32(Xs[row * XS_STRIDE + col]);
                    Xs[row * XS_STRIDE + col] = f32_to_bf16(o);
                }
            }
        __syncthreads();
#pragma unroll
        for (int it = 0; it < GITER; ++it) {
            int row = it * 8 + sub;
            *(short8*)(cur_out + ((size_t)(blk * R + row)) * 256 + c * 8) =
                *(const short8*)(&Xs[row * XS_STRIDE + c * 8]);
        }
    }
}

extern "C" void kernel_launch(void* const* d_in, const int* in_sizes, int n_in,
                              void* d_out, int out_size, void* d_ws, size_t ws_size,
                              hipStream_t stream) {
    const int*   tokens = (const int*)  d_in[0];
    const float* E      = (const float*)d_in[1];
    const float* W_in   = (const float*)d_in[2];
    const float* b_in   = (const float*)d_in[3];
    const float* W1     = (const float*)d_in[4];
    const float* b1     = (const float*)d_in[5];
    const float* W2     = (const float*)d_in[6];
    const float* b2     = (const float*)d_in[7];
    float* out = (float*)d_out;
    char* ws = (char*)d_ws;

    unsigned short* Ebf   = (unsigned short*)(ws);
    unsigned short* Winbf = (unsigned short*)(ws + 16416768);
    unsigned short* W1bf  = (unsigned short*)(ws + 16809984);
    unsigned short* W2bf  = (unsigned short*)(ws + 16941056);
    unsigned short* curA  = (unsigned short*)(ws + 17072128);
    unsigned short* curB  = (unsigned short*)(ws + 50626560);

    convert_f32_bf16<<<1024, 256, 0, stream>>>(E, W_in, W1, W2,
                                               Ebf, Winbf, W1bf, W2bf);

    const unsigned short* cin = curA;
    unsigned short* cout = curA;
    int first = 1;
    for (int L = 1024; L >= 1; L >>= 1) {
        int logL = 31 - __builtin_clz((unsigned)L);
        int last = (L == 1);
        // MT=4 (R=64) for big levels at 3 waves/EU (no spill, best bb L2
        // cover + weight amortization); MT=2 at L=256, MT=1 below.
        int MTs = (L >= 512) ? 4 : (L == 256 ? 2 : 1);
        int blocks = (64 * L) / (16 * MTs);
        if (MTs == 4)
            tree_level<4><<<dim3(blocks), dim3(256), 0, stream>>>(
                tokens, Ebf, Winbf, W1bf, W2bf, b_in, b1, b2,
                cin, last ? nullptr : cout, last ? out : nullptr, L, logL, first, last);
        else if (MTs == 2)
            tree_level<2><<<dim3(blocks), dim3(256), 0, stream>>>(
                tokens, Ebf, Winbf, W1bf, W2bf, b_in, b1, b2,
                cin, last ? nullptr : cout, last ? out : nullptr, L, logL, first, last);
        else
            tree_level<1><<<dim3(blocks), dim3(256), 0, stream>>>(
                tokens, Ebf, Winbf, W1bf, W2bf, b_in, b1, b2,
                cin, last ? nullptr : cout, last ? out : nullptr, L, logL, first, last);
        cin = cout;
        cout = (cout == curA) ? curB : curA;
        first = 0;
    }
}

// Round 4
// 475.071 us; speedup vs baseline: 1.1890x; 1.0646x over previous
//
#include <hip/hip_runtime.h>
#include <stdint.h>

// ---------------------------------------------------------------------------
// aggregated_embedding: heap binary-tree aggregation, 11 levels.
// Per level: out = root + (elu(elu(x@WinT+b_in)@W1T+b1)@W2T+b2), x=[root,left,right]
// bf16 MFMA 16x16x32, fp32 accumulate. Round 6:
//  THEORY (R1-R3 triangulation): level time bound by per-kstep WEIGHT
//  streaming from L2 (655MB @ L=1024, 64 FLOP/L2-byte, ~4.9TB/s sustained =
//  effective 312TF). Insensitive to occupancy & spill (R1==R3), sensitive to
//  per-row weight volume (R2 regression, volume 2x).
//  FIX: MT=8 (R=128 rows) for L>=512: weight volume halves (327MB), 128
//  FLOP/L2-byte. acc[8][4]=128 AGPR -> launch_bounds(256,2) (256 VGPR
//  budget, est live ~205, no spill). LDS 128*264*2=67.6KB -> dynamic LDS +
//  hipFuncSetAttribute (2 blocks/CU: 135KB < 160KB). No register gather
//  prefetch at MT=8 (g[16] wouldn't fit): serial stage phases, hidden by
//  co-resident block. L<=256 paths unchanged (still prefetched, MT=2/1).
// ws layout:
//   [0)            Ebf   32064*256 bf16
//   [16,416,768)   Winbf 256*768  bf16   (row-major [n][k] = MFMA B-frag order)
//   [16,809,984)   W1bf  256*256  bf16
//   [16,941,056)   W2bf  256*256  bf16
//   [17,072,128)   curA  64*1024*256 bf16
//   [50,626,560)   curB  64*512*256 bf16
// ---------------------------------------------------------------------------

typedef __attribute__((ext_vector_type(8))) short short8;   // 8 x bf16 frag
typedef __attribute__((ext_vector_type(4))) float f32x4;    // MFMA C/D

#define XS_STRIDE 264   // 256+8 pad: row stride 528B, b128-aligned, 2-way bank alias (free)
#define TOK_N 4095

__device__ __forceinline__ unsigned short f32_to_bf16(float f) {
    union { float f; unsigned u; } v; v.f = f;
    return (unsigned short)((v.u + 0x7fffu + ((v.u >> 16) & 1u)) >> 16);  // RNE
}
__device__ __forceinline__ float bf16_to_f32(unsigned short u) {
    union { unsigned u; float f; } v; v.u = ((unsigned)u) << 16; return v.f;
}

__global__ void convert_f32_bf16(const float* __restrict__ E,
                                 const float* __restrict__ Win,
                                 const float* __restrict__ W1,
                                 const float* __restrict__ W2,
                                 unsigned short* __restrict__ Ebf,
                                 unsigned short* __restrict__ Winbf,
                                 unsigned short* __restrict__ W1bf,
                                 unsigned short* __restrict__ W2bf) {
    const int nE = 32064 * 256, nWin = 256 * 768, nW = 256 * 256;
    const int total4 = (nE + nWin + 2 * nW) >> 2;
    for (int i = blockIdx.x * blockDim.x + threadIdx.x; i < total4;
         i += gridDim.x * blockDim.x) {
        int idx = i << 2;
        const float* src; unsigned short* dst; int off;
        if (idx < nE)                  { src = E;   dst = Ebf;   off = idx; }
        else if (idx < nE + nWin)      { src = Win; dst = Winbf; off = idx - nE; }
        else if (idx < nE + nWin + nW) { src = W1;  dst = W1bf;  off = idx - nE - nWin; }
        else                           { src = W2;  dst = W2bf;  off = idx - nE - nWin - nW; }
        float4 f = *(const float4*)(src + off);
        ushort4 o;
        o.x = f32_to_bf16(f.x); o.y = f32_to_bf16(f.y);
        o.z = f32_to_bf16(f.z); o.w = f32_to_bf16(f.w);
        *(ushort4*)(dst + off) = o;
    }
}

// ---------------------------------------------------------------------------
// tree_level<MT>: block = 256 thr (4 waves), R = MT*16 rows x 256 cols.
// Wave owns 64-col slice (n0), MT x 4 grid of 16x16 MFMA tiles.
// A-frag: lane holds A[m=lane&15][k=quad*8+j]; B-frag: W row-major 16B chunk.
// MT=8: 2 waves/EU (256 VGPR budget), dynamic LDS 67.6KB, serial gathers.
// ---------------------------------------------------------------------------
template<int MT>
__global__ __launch_bounds__(256, (MT == 8) ? 2 : 4)
void tree_level(const int* __restrict__ tokens,
                const unsigned short* __restrict__ Ebf,
                const unsigned short* __restrict__ Win,
                const unsigned short* __restrict__ W1,
                const unsigned short* __restrict__ W2,
                const float* __restrict__ b_in,
                const float* __restrict__ b1,
                const float* __restrict__ b2,
                const unsigned short* __restrict__ cur_in,
                unsigned short* __restrict__ cur_out,
                float* __restrict__ final_out,
                int L, int logL, int first, int last)
{
    constexpr int R = MT * 16;
    constexpr int GITER = R / 8;          // 16B-chunk gather iters per thread
    constexpr bool PF = (MT < 8);         // register gather prefetch (small MT)
    extern __shared__ unsigned short Xs[];

    const int tid  = threadIdx.x;
    const int lane = tid & 63;
    const int wid  = tid >> 6;
    const int l15  = lane & 15;
    const int q    = lane >> 4;
    const int n0   = wid * 64;
    const int blk  = blockIdx.x;
    const int c    = tid & 31;            // 16B chunk within 512B row
    const int sub  = tid >> 5;            // 8 rows gathered in parallel

    // gather source for (phase p, local row r)
    auto gsrc = [&](int p, int r) -> const unsigned short* {
        int g = blk * R + r;
        int b = g >> logL;
        int i = g - (b << logL);
        if (p == 0) {
            int tok = tokens[b * TOK_N + (L - 1) + i];
            return Ebf + (size_t)tok * 256;
        } else if (first) {
            int tok = tokens[b * TOK_N + 2047 + 2 * i + (p - 1)];
            return Ebf + (size_t)tok * 256;
        } else {
            return cur_in + ((size_t)b * (2 * L) + 2 * i + (p - 1)) * 256;
        }
    };

    // serial stage (MT==8 path): transient regs, die at the write
    auto stage = [&](int p) {
        short8 t[GITER];
#pragma unroll
        for (int it = 0; it < GITER; ++it)
            t[it] = *(const short8*)(gsrc(p, it * 8 + sub) + c * 8);
#pragma unroll
        for (int it = 0; it < GITER; ++it)
            *(short8*)(&Xs[(it * 8 + sub) * XS_STRIDE + c * 8]) = t[it];
    };

    f32x4 acc[MT][4];

    // shared GEMM: 8 ksteps of K=256 against a [n][k] weight panel
    auto run_gemm = [&](const unsigned short* base, int nstride, int kbase) {
        short8 bb[2][4];                              // rolling 2-kstep preload
#pragma unroll
        for (int k = 0; k < 2; ++k)
#pragma unroll
            for (int nt = 0; nt < 4; ++nt)
                bb[k][nt] = *(const short8*)(base + (size_t)(nt * 16) * nstride + kbase + k * 32);
#pragma unroll
        for (int k = 0; k < 8; ++k) {
            short8 a[MT];
#pragma unroll
            for (int mt = 0; mt < MT; ++mt)
                a[mt] = *(const short8*)(&Xs[(mt * 16 + l15) * XS_STRIDE + k * 32 + q * 8]);
#pragma unroll
            for (int mt = 0; mt < MT; ++mt)
#pragma unroll
                for (int nt = 0; nt < 4; ++nt)
                    acc[mt][nt] = __builtin_amdgcn_mfma_f32_16x16x32_bf16(
                        a[mt], bb[k & 1][nt], acc[mt][nt], 0, 0, 0);
            if (k + 2 < 8) {
#pragma unroll
                for (int nt = 0; nt < 4; ++nt)
                    bb[k & 1][nt] = *(const short8*)(base + (size_t)(nt * 16) * nstride + kbase + (k + 2) * 32);
            }
        }
    };

    auto acc_init = [&](const float* __restrict__ b) {
        float bv[4];
#pragma unroll
        for (int nt = 0; nt < 4; ++nt) bv[nt] = b[n0 + nt * 16 + l15];
#pragma unroll
        for (int mt = 0; mt < MT; ++mt)
#pragma unroll
            for (int nt = 0; nt < 4; ++nt)
                acc[mt][nt] = (f32x4){bv[nt], bv[nt], bv[nt], bv[nt]};
    };

    auto elu_to_Xs = [&]() {
#pragma unroll
        for (int mt = 0; mt < MT; ++mt)
#pragma unroll
            for (int nt = 0; nt < 4; ++nt)
#pragma unroll
                for (int r = 0; r < 4; ++r) {
                    float h = acc[mt][nt][r];
                    h = h > 0.f ? h : (__expf(h) - 1.f);
                    Xs[(mt * 16 + q * 4 + r) * XS_STRIDE + n0 + nt * 16 + l15] = f32_to_bf16(h);
                }
    };

    short8 g[PF ? GITER : 1];             // persistent prefetch regs (MT<8 only)

    // ---- phase-0 gather (root) ------------------------------------------
    if constexpr (PF) {
#pragma unroll
        for (int it = 0; it < GITER; ++it)
            g[it] = *(const short8*)(gsrc(0, it * 8 + sub) + c * 8);
#pragma unroll
        for (int it = 0; it < GITER; ++it)
            *(short8*)(&Xs[(it * 8 + sub) * XS_STRIDE + c * 8]) = g[it];
    } else {
        stage(0);
    }
    __syncthreads();

    // ---- GEMM1: 3 phases of K=256 against Win (row stride 768) ----------
    acc_init(b_in);
    const unsigned short* wbase = Win + q * 8 + (size_t)(n0 + l15) * 768;
    for (int p = 0; p < 3; ++p) {
        if constexpr (PF) {
            if (p < 2) {                              // prefetch next gather
#pragma unroll
                for (int it = 0; it < GITER; ++it)
                    g[it] = *(const short8*)(gsrc(p + 1, it * 8 + sub) + c * 8);
            }
        }
        run_gemm(wbase, 768, p * 256);
        __syncthreads();                               // all waves done reading Xs
        if (p < 2) {
            if constexpr (PF) {
#pragma unroll
                for (int it = 0; it < GITER; ++it)
                    *(short8*)(&Xs[(it * 8 + sub) * XS_STRIDE + c * 8]) = g[it];
            } else {
                stage(p + 1);                          // serial stage (MT==8)
            }
            __syncthreads();
        }
    }

    // ---- epilogue 1: Xs = bf16(elu(H1)) in place ------------------------
    elu_to_Xs();
    __syncthreads();

    // ---- GEMM2: H2 = elu(H1) @ W1^T  (+ root re-gather prefetch if PF) --
    acc_init(b1);
    if constexpr (PF) {
        // residual root (bf16) re-gather: issued here, consumed after GEMM3
#pragma unroll
        for (int it = 0; it < GITER; ++it)
            g[it] = *(const short8*)(gsrc(0, it * 8 + sub) + c * 8);
    }
    run_gemm(W1 + q * 8 + (size_t)(n0 + l15) * 256, 256, 0);
    __syncthreads();

    // ---- epilogue 2: Xs = bf16(elu(H2)) in place ------------------------
    elu_to_Xs();
    __syncthreads();

    // ---- GEMM3: H3 = elu(H2) @ W2^T -------------------------------------
    acc_init(b2);
    run_gemm(W2 + q * 8 + (size_t)(n0 + l15) * 256, 256, 0);
    __syncthreads();
    // park the root rows (bf16) in Xs for transposed access by the epilogue
    if constexpr (PF) {
#pragma unroll
        for (int it = 0; it < GITER; ++it)
            *(short8*)(&Xs[(it * 8 + sub) * XS_STRIDE + c * 8]) = g[it];
    } else {
        stage(0);                                      // serial root re-gather
    }
    __syncthreads();

    // ---- epilogue 3: out = root + H3 (+b2 already in acc), no elu -------
    if (last) {
        // final level: 4 blocks total, fp32 output, scalar path is fine
#pragma unroll
        for (int mt = 0; mt < MT; ++mt)
#pragma unroll
            for (int r = 0; r < 4; ++r) {
                int row = mt * 16 + q * 4 + r;
                int gg  = blk * R + row;
#pragma unroll
                for (int nt = 0; nt < 4; ++nt) {
                    int col = n0 + nt * 16 + l15;
                    float o = acc[mt][nt][r] + bf16_to_f32(Xs[row * XS_STRIDE + col]);
                    final_out[(size_t)gg * 256 + col] = o;
                }
            }
    } else {
        // add root into acc, write bf16 result back into Xs IN PLACE
        // (each thread reads+writes the exact same address: no race),
        // then store fully-coalesced short8 rows.
#pragma unroll
        for (int mt = 0; mt < MT; ++mt)
#pragma unroll
            for (int r = 0; r < 4; ++r) {
                int row = mt * 16 + q * 4 + r;
#pragma unroll
                for (int nt = 0; nt < 4; ++nt) {
                    int col = n0 + nt * 16 + l15;
                    float o = acc[mt][nt][r] + bf16_to_f32(Xs[row * XS_STRIDE + col]);
                    Xs[row * XS_STRIDE + col] = f32_to_bf16(o);
                }
            }
        __syncthreads();
#pragma unroll
        for (int it = 0; it < GITER; ++it) {
            int row = it * 8 + sub;
            *(short8*)(cur_out + ((size_t)(blk * R + row)) * 256 + c * 8) =
                *(const short8*)(&Xs[row * XS_STRIDE + c * 8]);
        }
    }
}

extern "C" void kernel_launch(void* const* d_in, const int* in_sizes, int n_in,
                              void* d_out, int out_size, void* d_ws, size_t ws_size,
                              hipStream_t stream) {
    const int*   tokens = (const int*)  d_in[0];
    const float* E      = (const float*)d_in[1];
    const float* W_in   = (const float*)d_in[2];
    const float* b_in   = (const float*)d_in[3];
    const float* W1     = (const float*)d_in[4];
    const float* b1     = (const float*)d_in[5];
    const float* W2     = (const float*)d_in[6];
    const float* b2     = (const float*)d_in[7];
    float* out = (float*)d_out;
    char* ws = (char*)d_ws;

    unsigned short* Ebf   = (unsigned short*)(ws);
    unsigned short* Winbf = (unsigned short*)(ws + 16416768);
    unsigned short* W1bf  = (unsigned short*)(ws + 16809984);
    unsigned short* W2bf  = (unsigned short*)(ws + 16941056);
    unsigned short* curA  = (unsigned short*)(ws + 17072128);
    unsigned short* curB  = (unsigned short*)(ws + 50626560);

    // allow 67.6KB dynamic LDS for the MT=8 instantiation (once per process)
    static bool attr_done = false;
    if (!attr_done) {
        void (*kfn)(const int*, const unsigned short*, const unsigned short*,
                    const unsigned short*, const unsigned short*, const float*,
                    const float*, const float*, const unsigned short*,
                    unsigned short*, float*, int, int, int, int) = tree_level<8>;
        (void)hipFuncSetAttribute(reinterpret_cast<const void*>(kfn),
                                  hipFuncAttributeMaxDynamicSharedMemorySize,
                                  128 * XS_STRIDE * 2);
        attr_done = true;
    }

    convert_f32_bf16<<<1024, 256, 0, stream>>>(E, W_in, W1, W2,
                                               Ebf, Winbf, W1bf, W2bf);

    const unsigned short* cin = curA;
    unsigned short* cout = curA;
    int first = 1;
    for (int L = 1024; L >= 1; L >>= 1) {
        int logL = 31 - __builtin_clz((unsigned)L);
        int last = (L == 1);
        // MT=8 (R=128) for big levels: halves per-level L2 weight volume.
        int MTs = (L >= 512) ? 8 : (L == 256 ? 2 : 1);
        int R = 16 * MTs;
        int blocks = (64 * L) / R;
        size_t shmem = (size_t)R * XS_STRIDE * 2;
        if (MTs == 8)
            tree_level<8><<<dim3(blocks), dim3(256), shmem, stream>>>(
                tokens, Ebf, Winbf, W1bf, W2bf, b_in, b1, b2,
                cin, last ? nullptr : cout, last ? out : nullptr, L, logL, first, last);
        else if (MTs == 2)
            tree_level<2><<<dim3(blocks), dim3(256), shmem, stream>>>(
                tokens, Ebf, Winbf, W1bf, W2bf, b_in, b1, b2,
                cin, last ? nullptr : cout, last ? out : nullptr, L, logL, first, last);
        else
            tree_level<1><<<dim3(blocks), dim3(256), shmem, stream>>>(
                tokens, Ebf, Winbf, W1bf, W2bf, b_in, b1, b2,
                cin, last ? nullptr : cout, last ? out : nullptr, L, logL, first, last);
        cin = cout;
        cout = (cout == curA) ? curB : curA;
        first = 0;
    }
}